// Round 1
// baseline (1007.927 us; speedup 1.0000x reference)
//
#include <hip/hip_runtime.h>

// GCN encoder: conv1(512->256) -> BN -> ReLU -> conv2(256->128) -> BN
// Strategy: build CSR by dst once per call (ws is re-poisoned), project-then-
// aggregate (GEMM before scatter so aggregation runs at the small dim),
// wave-per-node CSR aggregation (no float atomics), bf16 intermediate storage
// (halves gather BW; threshold 0.1 tolerates ~0.4% rel error), fp32 accum.

#define NN 50000
#define NE 1600000
#define DIN 512
#define D1 256
#define D2 128
#define EPSV 1e-5f

__device__ __forceinline__ float bf2f(unsigned short u) {
  return __uint_as_float(((unsigned int)u) << 16);
}
__device__ __forceinline__ unsigned short f2bf(float f) {
  unsigned int u = __float_as_uint(f);
  u += 0x7fffu + ((u >> 16) & 1u);   // RNE
  return (unsigned short)(u >> 16);
}

// ---------- CSR build ----------
__global__ void k_zero(int* __restrict__ cnt, float* __restrict__ stats) {
  int i = blockIdx.x * blockDim.x + threadIdx.x;
  if (i < NN) cnt[i] = 0;
  if (i < (D1 * 2 + D2 * 2)) stats[i] = 0.0f;
}

__global__ void k_hist(const int* __restrict__ dst, int* __restrict__ cnt) {
  int e = blockIdx.x * blockDim.x + threadIdx.x;
  if (e < NE) atomicAdd(&cnt[dst[e]], 1);
}

__global__ void k_scan_partial(const int* __restrict__ cnt, int* __restrict__ part) {
  __shared__ int s[256];
  int t = threadIdx.x;
  int i = blockIdx.x * 256 + t;
  s[t] = (i < NN) ? cnt[i] : 0;
  __syncthreads();
  for (int off = 128; off > 0; off >>= 1) {
    if (t < off) s[t] += s[t + off];
    __syncthreads();
  }
  if (t == 0) part[blockIdx.x] = s[0];
}

__global__ void k_scan_block(int* __restrict__ part, int nb) {
  __shared__ int s[256];
  int t = threadIdx.x;
  int v = (t < nb) ? part[t] : 0;
  s[t] = v;
  __syncthreads();
  for (int off = 1; off < 256; off <<= 1) {
    int add = (t >= off) ? s[t - off] : 0;
    __syncthreads();
    s[t] += add;
    __syncthreads();
  }
  part[t] = s[t] - v;  // exclusive block offsets
}

__global__ void k_scan_final(const int* __restrict__ cnt, const int* __restrict__ boff,
                             int* __restrict__ row_ptr, int* __restrict__ cursor,
                             float* __restrict__ dis) {
  __shared__ int s[256];
  int t = threadIdx.x;
  int i = blockIdx.x * 256 + t;
  int v = (i < NN) ? cnt[i] : 0;
  s[t] = v;
  __syncthreads();
  for (int off = 1; off < 256; off <<= 1) {
    int add = (t >= off) ? s[t - off] : 0;
    __syncthreads();
    s[t] += add;
    __syncthreads();
  }
  if (i < NN) {
    int excl = boff[blockIdx.x] + s[t] - v;
    row_ptr[i] = excl;
    cursor[i] = excl;
    dis[i] = rsqrtf((float)(v + 1));  // self-loop guarantees deg>=1
    if (i == NN - 1) row_ptr[NN] = excl + v;
  }
}

__global__ void k_fill(const int* __restrict__ src, const int* __restrict__ dst,
                       int* __restrict__ cursor, int* __restrict__ col) {
  int e = blockIdx.x * blockDim.x + threadIdx.x;
  if (e < NE) {
    int d = dst[e];
    int pos = atomicAdd(&cursor[d], 1);
    col[pos] = src[e];
  }
}

// ---------- GEMM (fp32 accumulate, bf16 out) ----------
__device__ __forceinline__ float ldc(const float* p) { return *p; }
__device__ __forceinline__ float ldc(const unsigned short* p) { return bf2f(*p); }

template <typename TA, int K>
__global__ __launch_bounds__(256) void k_gemm(const TA* __restrict__ A,
                                              const float* __restrict__ B,
                                              unsigned short* __restrict__ C,
                                              int M, int N) {
  // 64x64 block tile, BK=32, 4x4 per thread.
  __shared__ float As[64][33];  // [m][k], +1 pad breaks write conflicts
  __shared__ float Bs[32][64];  // [k][n], 64 stride -> aligned b128 reads
  int t = threadIdx.x;
  int m0 = blockIdx.x * 64, n0 = blockIdx.y * 64;
  int tx = t & 15, ty = t >> 4;
  float acc[4][4] = {};
  for (int k0 = 0; k0 < K; k0 += 32) {
#pragma unroll
    for (int i = 0; i < 8; i++) {
      int idx = t + i * 256;
      int m = idx >> 5, k = idx & 31;
      int gm = m0 + m;
      As[m][k] = (gm < M) ? ldc(&A[(size_t)gm * K + k0 + k]) : 0.0f;
    }
#pragma unroll
    for (int i = 0; i < 8; i++) {
      int idx = t + i * 256;
      int k = idx >> 6, n = idx & 63;
      Bs[k][n] = B[(size_t)(k0 + k) * N + n0 + n];  // N%64==0
    }
    __syncthreads();
#pragma unroll
    for (int kk = 0; kk < 32; kk++) {
      float a[4], b[4];
#pragma unroll
      for (int i = 0; i < 4; i++) a[i] = As[ty * 4 + i][kk];
#pragma unroll
      for (int j = 0; j < 4; j++) b[j] = Bs[kk][tx * 4 + j];
#pragma unroll
      for (int i = 0; i < 4; i++)
#pragma unroll
        for (int j = 0; j < 4; j++) acc[i][j] += a[i] * b[j];
    }
    __syncthreads();
  }
#pragma unroll
  for (int i = 0; i < 4; i++) {
    int gm = m0 + ty * 4 + i;
    if (gm < M) {
      ushort4 o;
      o.x = f2bf(acc[i][0]);
      o.y = f2bf(acc[i][1]);
      o.z = f2bf(acc[i][2]);
      o.w = f2bf(acc[i][3]);
      *(ushort4*)(&C[(size_t)gm * N + n0 + tx * 4]) = o;
    }
  }
}

// ---------- CSR aggregation: one wave per node ----------
__global__ __launch_bounds__(256) void k_agg1(const unsigned short* __restrict__ H,
                                              const int* __restrict__ row_ptr,
                                              const int* __restrict__ col,
                                              const float* __restrict__ dis,
                                              const float* __restrict__ bias,
                                              unsigned short* __restrict__ OUT) {
  int n = blockIdx.x * 4 + (threadIdx.x >> 6);
  int lane = threadIdx.x & 63;
  if (n >= NN) return;
  float dn = dis[n];
  ushort4 v = ((const ushort4*)(H + (size_t)n * D1))[lane];
  float wsf = dn * dn;
  float a0 = wsf * bf2f(v.x), a1 = wsf * bf2f(v.y);
  float a2 = wsf * bf2f(v.z), a3 = wsf * bf2f(v.w);
  int e = row_ptr[n], e1 = row_ptr[n + 1];
  for (; e + 1 < e1; e += 2) {
    int sa = col[e], sb = col[e + 1];
    float wa = dis[sa] * dn, wb = dis[sb] * dn;
    ushort4 ua = ((const ushort4*)(H + (size_t)sa * D1))[lane];
    ushort4 ub = ((const ushort4*)(H + (size_t)sb * D1))[lane];
    a0 += wa * bf2f(ua.x) + wb * bf2f(ub.x);
    a1 += wa * bf2f(ua.y) + wb * bf2f(ub.y);
    a2 += wa * bf2f(ua.z) + wb * bf2f(ub.z);
    a3 += wa * bf2f(ua.w) + wb * bf2f(ub.w);
  }
  if (e < e1) {
    int sa = col[e];
    float wa = dis[sa] * dn;
    ushort4 ua = ((const ushort4*)(H + (size_t)sa * D1))[lane];
    a0 += wa * bf2f(ua.x);
    a1 += wa * bf2f(ua.y);
    a2 += wa * bf2f(ua.z);
    a3 += wa * bf2f(ua.w);
  }
  int c = lane * 4;
  a0 += bias[c]; a1 += bias[c + 1]; a2 += bias[c + 2]; a3 += bias[c + 3];
  ushort4 o;
  o.x = f2bf(a0); o.y = f2bf(a1); o.z = f2bf(a2); o.w = f2bf(a3);
  ((ushort4*)(OUT + (size_t)n * D1))[lane] = o;
}

__global__ __launch_bounds__(256) void k_agg2(const unsigned short* __restrict__ H,
                                              const int* __restrict__ row_ptr,
                                              const int* __restrict__ col,
                                              const float* __restrict__ dis,
                                              const float* __restrict__ bias,
                                              float* __restrict__ OUT) {
  int n = blockIdx.x * 4 + (threadIdx.x >> 6);
  int lane = threadIdx.x & 63;
  if (n >= NN) return;
  float dn = dis[n];
  ushort2 v = ((const ushort2*)(H + (size_t)n * D2))[lane];
  float wsf = dn * dn;
  float a0 = wsf * bf2f(v.x), a1 = wsf * bf2f(v.y);
  int e = row_ptr[n], e1 = row_ptr[n + 1];
  for (; e + 1 < e1; e += 2) {
    int sa = col[e], sb = col[e + 1];
    float wa = dis[sa] * dn, wb = dis[sb] * dn;
    ushort2 ua = ((const ushort2*)(H + (size_t)sa * D2))[lane];
    ushort2 ub = ((const ushort2*)(H + (size_t)sb * D2))[lane];
    a0 += wa * bf2f(ua.x) + wb * bf2f(ub.x);
    a1 += wa * bf2f(ua.y) + wb * bf2f(ub.y);
  }
  if (e < e1) {
    int sa = col[e];
    float wa = dis[sa] * dn;
    ushort2 ua = ((const ushort2*)(H + (size_t)sa * D2))[lane];
    a0 += wa * bf2f(ua.x);
    a1 += wa * bf2f(ua.y);
  }
  int c = lane * 2;
  a0 += bias[c]; a1 += bias[c + 1];
  ((float2*)(OUT + (size_t)n * D2))[lane] = make_float2(a0, a1);
}

// ---------- BatchNorm ----------
__global__ void k_stats1(const unsigned short* __restrict__ X, float* __restrict__ stats) {
  int t = threadIdx.x;            // column 0..255
  int r0 = blockIdx.x * 64;
  int r1 = (r0 + 64 < NN) ? r0 + 64 : NN;
  float s = 0.f, q = 0.f;
  for (int r = r0; r < r1; r++) {
    float v = bf2f(X[(size_t)r * D1 + t]);
    s += v;
    q += v * v;
  }
  atomicAdd(&stats[t], s);
  atomicAdd(&stats[D1 + t], q);
}

__global__ void k_apply1(unsigned short* __restrict__ X, const float* __restrict__ stats,
                         const float* __restrict__ gamma, const float* __restrict__ beta) {
  int i = blockIdx.x * blockDim.x + threadIdx.x;  // NN*D1 exact multiple of 256
  int c = i & (D1 - 1);
  float mean = stats[c] * (1.0f / NN);
  float var = stats[D1 + c] * (1.0f / NN) - mean * mean;
  float sc = gamma[c] * rsqrtf(var + EPSV);
  float v = (bf2f(X[i]) - mean) * sc + beta[c];
  X[i] = f2bf(fmaxf(v, 0.0f));  // fused ReLU
}

__global__ void k_stats2(const float* __restrict__ X, float* __restrict__ stats) {
  int t = threadIdx.x;            // column 0..127
  int r0 = blockIdx.x * 128;
  int r1 = (r0 + 128 < NN) ? r0 + 128 : NN;
  float s = 0.f, q = 0.f;
  for (int r = r0; r < r1; r++) {
    float v = X[(size_t)r * D2 + t];
    s += v;
    q += v * v;
  }
  atomicAdd(&stats[t], s);
  atomicAdd(&stats[D2 + t], q);
}

__global__ void k_apply2(float* __restrict__ X, const float* __restrict__ stats,
                         const float* __restrict__ gamma, const float* __restrict__ beta) {
  int i = blockIdx.x * blockDim.x + threadIdx.x;  // NN*D2 exact multiple of 256
  int c = i & (D2 - 1);
  float mean = stats[c] * (1.0f / NN);
  float var = stats[D2 + c] * (1.0f / NN) - mean * mean;
  float sc = gamma[c] * rsqrtf(var + EPSV);
  X[i] = (X[i] - mean) * sc + beta[c];
}

extern "C" void kernel_launch(void* const* d_in, const int* in_sizes, int n_in,
                              void* d_out, int out_size, void* d_ws, size_t ws_size,
                              hipStream_t stream) {
  const float* x  = (const float*)d_in[0];
  const int* ei   = (const int*)d_in[1];   // [2, NE] row-major, int32
  const int* srcv = ei;
  const int* dstv = ei + NE;
  const float* W1  = (const float*)d_in[2];
  const float* b1  = (const float*)d_in[3];
  const float* g1  = (const float*)d_in[4];
  const float* be1 = (const float*)d_in[5];
  const float* W2  = (const float*)d_in[6];
  const float* b2  = (const float*)d_in[7];
  const float* g2  = (const float*)d_in[8];
  const float* be2 = (const float*)d_in[9];
  float* out = (float*)d_out;

  // Workspace layout (~71 MB total)
  char* ws = (char*)d_ws;
  size_t off = 0;
  auto alloc = [&](size_t bytes) {
    size_t cur = off;
    off = (off + bytes + 255) & ~(size_t)255;
    return cur;
  };
  int* cnt       = (int*)(ws + alloc(NN * 4));
  int* row_ptr   = (int*)(ws + alloc((NN + 1) * 4));
  int* cursor    = (int*)(ws + alloc(NN * 4));
  float* dis     = (float*)(ws + alloc(NN * 4));
  int* part      = (int*)(ws + alloc(256 * 4));
  float* stats   = (float*)(ws + alloc((D1 * 2 + D2 * 2) * 4));
  int* col       = (int*)(ws + alloc((size_t)NE * 4));
  unsigned short* H1 = (unsigned short*)(ws + alloc((size_t)NN * D1 * 2));
  unsigned short* A1 = (unsigned short*)(ws + alloc((size_t)NN * D1 * 2));
  unsigned short* H2 = (unsigned short*)(ws + alloc((size_t)NN * D2 * 2));
  float* stats2 = stats + D1 * 2;

  const int nb = (NN + 255) / 256;  // 196

  // CSR build
  k_zero<<<nb, 256, 0, stream>>>(cnt, stats);
  k_hist<<<NE / 256, 256, 0, stream>>>(dstv, cnt);
  k_scan_partial<<<nb, 256, 0, stream>>>(cnt, part);
  k_scan_block<<<1, 256, 0, stream>>>(part, nb);
  k_scan_final<<<nb, 256, 0, stream>>>(cnt, part, row_ptr, cursor, dis);
  k_fill<<<NE / 256, 256, 0, stream>>>(srcv, dstv, cursor, col);

  // conv1: H1 = x@W1 ; A1 = agg(H1)+b1 ; BN1+ReLU in place on A1
  k_gemm<float, DIN><<<dim3((NN + 63) / 64, D1 / 64), 256, 0, stream>>>(x, W1, H1, NN, D1);
  k_agg1<<<(NN + 3) / 4, 256, 0, stream>>>(H1, row_ptr, col, dis, b1, A1);
  k_stats1<<<(NN + 63) / 64, 256, 0, stream>>>(A1, stats);
  k_apply1<<<NN * D1 / 256, 256, 0, stream>>>(A1, stats, g1, be1);

  // conv2: H2 = A1@W2 ; out = agg(H2)+b2 ; BN2 in place on out
  k_gemm<unsigned short, D1><<<dim3((NN + 63) / 64, D2 / 64), 256, 0, stream>>>(A1, W2, H2, NN, D2);
  k_agg2<<<(NN + 3) / 4, 256, 0, stream>>>(H2, row_ptr, col, dis, b2, out);
  k_stats2<<<(NN + 127) / 128, 128, 0, stream>>>(out, stats2);
  k_apply2<<<NN * D2 / 256, 256, 0, stream>>>(out, stats2, g2, be2);
}

// Round 2
// 740.151 us; speedup vs baseline: 1.3618x; 1.3618x over previous
//
#include <hip/hip_runtime.h>
#include <hip/hip_bf16.h>

// GCN encoder: conv1(512->256) -> BN -> ReLU -> conv2(256->128) -> BN
// R2: both GEMMs moved to bf16 MFMA (16x16x32), 128x128 tile, BK=64,
// XOR-swizzled LDS, global_load_lds width-16 staging for bf16 operands,
// fused fp32->bf16 conversion in GEMM1's A staging (no extra ws, no extra pass).

#define NN 50000
#define NE 1600000
#define DIN 512
#define D1 256
#define D2 128
#define EPSV 1e-5f

typedef __attribute__((ext_vector_type(8))) short bf16x8_t;
typedef __attribute__((ext_vector_type(4))) float f32x4_t;

__device__ __forceinline__ float bf2f(unsigned short u) {
  return __uint_as_float(((unsigned int)u) << 16);
}
__device__ __forceinline__ unsigned short f2bf(float f) {
  unsigned int u = __float_as_uint(f);
  u += 0x7fffu + ((u >> 16) & 1u);   // RNE
  return (unsigned short)(u >> 16);
}
__device__ __forceinline__ unsigned int pk2(float a, float b) {
  __hip_bfloat162 h = __float22bfloat162_rn(make_float2(a, b));
  union { __hip_bfloat162 h; unsigned int u; } c;
  c.h = h;
  return c.u;
}

// ---------- CSR build ----------
__global__ void k_zero(int* __restrict__ cnt, float* __restrict__ stats) {
  int i = blockIdx.x * blockDim.x + threadIdx.x;
  if (i < NN) cnt[i] = 0;
  if (i < (D1 * 2 + D2 * 2)) stats[i] = 0.0f;
}

__global__ void k_hist(const int* __restrict__ dst, int* __restrict__ cnt) {
  int e = blockIdx.x * blockDim.x + threadIdx.x;
  if (e < NE) atomicAdd(&cnt[dst[e]], 1);
}

__global__ void k_scan_partial(const int* __restrict__ cnt, int* __restrict__ part) {
  __shared__ int s[256];
  int t = threadIdx.x;
  int i = blockIdx.x * 256 + t;
  s[t] = (i < NN) ? cnt[i] : 0;
  __syncthreads();
  for (int off = 128; off > 0; off >>= 1) {
    if (t < off) s[t] += s[t + off];
    __syncthreads();
  }
  if (t == 0) part[blockIdx.x] = s[0];
}

__global__ void k_scan_block(int* __restrict__ part, int nb) {
  __shared__ int s[256];
  int t = threadIdx.x;
  int v = (t < nb) ? part[t] : 0;
  s[t] = v;
  __syncthreads();
  for (int off = 1; off < 256; off <<= 1) {
    int add = (t >= off) ? s[t - off] : 0;
    __syncthreads();
    s[t] += add;
    __syncthreads();
  }
  part[t] = s[t] - v;  // exclusive block offsets
}

__global__ void k_scan_final(const int* __restrict__ cnt, const int* __restrict__ boff,
                             int* __restrict__ row_ptr, int* __restrict__ cursor,
                             float* __restrict__ dis) {
  __shared__ int s[256];
  int t = threadIdx.x;
  int i = blockIdx.x * 256 + t;
  int v = (i < NN) ? cnt[i] : 0;
  s[t] = v;
  __syncthreads();
  for (int off = 1; off < 256; off <<= 1) {
    int add = (t >= off) ? s[t - off] : 0;
    __syncthreads();
    s[t] += add;
    __syncthreads();
  }
  if (i < NN) {
    int excl = boff[blockIdx.x] + s[t] - v;
    row_ptr[i] = excl;
    cursor[i] = excl;
    dis[i] = rsqrtf((float)(v + 1));  // self-loop guarantees deg>=1
    if (i == NN - 1) row_ptr[NN] = excl + v;
  }
}

__global__ void k_fill(const int* __restrict__ src, const int* __restrict__ dst,
                       int* __restrict__ cursor, int* __restrict__ col) {
  int e = blockIdx.x * blockDim.x + threadIdx.x;
  if (e < NE) {
    int d = dst[e];
    int pos = atomicAdd(&cursor[d], 1);
    col[pos] = src[e];
  }
}

// ---------- weight prep: W [KxN] fp32 -> Wt [NxK] bf16 ----------
__global__ void k_prep_w(const float* __restrict__ W1, const float* __restrict__ W2,
                         unsigned short* __restrict__ W1t, unsigned short* __restrict__ W2t) {
  int i = blockIdx.x * 256 + threadIdx.x;
  if (i < DIN * D1) {  // W1t[n*DIN + k] = W1[k*D1 + n]
    int n = i / DIN, k = i - n * DIN;
    W1t[i] = f2bf(W1[(size_t)k * D1 + n]);
  } else {
    int j = i - DIN * D1;  // W2t[n*D1 + k] = W2[k*D2 + n]
    int n = j / D1, k = j - n * D1;
    W2t[j] = f2bf(W2[(size_t)k * D2 + n]);
  }
}

// ---------- MFMA GEMM: C[MxN] bf16 = A[MxK] @ Bt[NxK]^T, fp32 accum ----------
// 128x128 block tile, BK=64, 4 waves (2x2), each wave 64x64 via 4x4 MFMA 16x16x32.
// LDS layout: X[row][64] bf16 with XOR swizzle: physical 8-elem block pb holds
// logical k-block pb ^ (row&7). Compatible with global_load_lds (contiguous
// wave chunk = 8 rows x 128B) and conflict-reduced ds_read_b128 fragment loads.
template <int K, bool A_IS_F32>
__global__ __launch_bounds__(256) void k_gemm_mfma(const void* __restrict__ Ap,
                                                   const unsigned short* __restrict__ Bt,
                                                   unsigned short* __restrict__ C,
                                                   int M, int N) {
  __shared__ unsigned short As[128 * 64];
  __shared__ unsigned short Bs[128 * 64];
  const int t = threadIdx.x;
  const int wave = t >> 6, lane = t & 63;
  const int m0 = blockIdx.x * 128, n0 = blockIdx.y * 128;
  const int wm = (wave >> 1) * 64, wn = (wave & 1) * 64;
  const int l8 = lane >> 3;
  const int lbs = (lane & 7) ^ l8;  // logical k-block for staging
  const int row_c = lane & 15, quad = lane >> 4;

  f32x4_t acc[4][4];
#pragma unroll
  for (int i = 0; i < 4; i++)
#pragma unroll
    for (int j = 0; j < 4; j++) acc[i][j] = (f32x4_t){0.f, 0.f, 0.f, 0.f};

  for (int k0 = 0; k0 < K; k0 += 64) {
    // --- stage B: bf16, async direct-to-LDS ---
#pragma unroll
    for (int j = 0; j < 4; j++) {
      int chunk = wave * 4 + j;
      int row = chunk * 8 + l8;
      const unsigned short* g = Bt + (size_t)(n0 + row) * K + k0 + lbs * 8;
      __builtin_amdgcn_global_load_lds(
          (const __attribute__((address_space(1))) unsigned int*)g,
          (__attribute__((address_space(3))) unsigned int*)(Bs + chunk * 512), 16, 0, 0);
    }
    // --- stage A ---
    if (A_IS_F32) {
      const float* A = (const float*)Ap;
#pragma unroll
      for (int i = 0; i < 4; i++) {
        int bid = i * 256 + t;
        int row = bid >> 3, pb = bid & 7;
        int lb = pb ^ (row & 7);
        int gm = m0 + row;
        if (gm >= M) gm = M - 1;
        const float4* s = (const float4*)(A + (size_t)gm * K + k0 + lb * 8);
        float4 v0 = s[0], v1 = s[1];
        uint4 o;
        o.x = pk2(v0.x, v0.y);
        o.y = pk2(v0.z, v0.w);
        o.z = pk2(v1.x, v1.y);
        o.w = pk2(v1.z, v1.w);
        *(uint4*)(As + row * 64 + pb * 8) = o;
      }
    } else {
      const unsigned short* A = (const unsigned short*)Ap;
#pragma unroll
      for (int j = 0; j < 4; j++) {
        int chunk = wave * 4 + j;
        int row = chunk * 8 + l8;
        int gm = m0 + row;
        if (gm >= M) gm = M - 1;
        const unsigned short* g = A + (size_t)gm * K + k0 + lbs * 8;
        __builtin_amdgcn_global_load_lds(
            (const __attribute__((address_space(1))) unsigned int*)g,
            (__attribute__((address_space(3))) unsigned int*)(As + chunk * 512), 16, 0, 0);
      }
    }
    __syncthreads();
#pragma unroll
    for (int ki = 0; ki < 2; ki++) {
      bf16x8_t af[4], bfr[4];
      int kb = ki * 4 + quad;
#pragma unroll
      for (int i = 0; i < 4; i++) {
        int ar = wm + i * 16 + row_c;
        af[i] = *(const bf16x8_t*)(As + ar * 64 + ((kb ^ (ar & 7)) * 8));
        int br = wn + i * 16 + row_c;
        bfr[i] = *(const bf16x8_t*)(Bs + br * 64 + ((kb ^ (br & 7)) * 8));
      }
#pragma unroll
      for (int i = 0; i < 4; i++)
#pragma unroll
        for (int j = 0; j < 4; j++)
          acc[i][j] = __builtin_amdgcn_mfma_f32_16x16x32_bf16(af[i], bfr[j], acc[i][j], 0, 0, 0);
    }
    __syncthreads();
  }
  // epilogue: C/D layout col=lane&15, row=quad*4+reg
#pragma unroll
  for (int i = 0; i < 4; i++) {
#pragma unroll
    for (int j = 0; j < 4; j++) {
      int col = n0 + wn + j * 16 + row_c;
#pragma unroll
      for (int r = 0; r < 4; r++) {
        int gm = m0 + wm + i * 16 + quad * 4 + r;
        if (gm < M) C[(size_t)gm * N + col] = f2bf(acc[i][j][r]);
      }
    }
  }
}

// ---------- CSR aggregation: one wave per node ----------
__global__ __launch_bounds__(256) void k_agg1(const unsigned short* __restrict__ H,
                                              const int* __restrict__ row_ptr,
                                              const int* __restrict__ col,
                                              const float* __restrict__ dis,
                                              const float* __restrict__ bias,
                                              unsigned short* __restrict__ OUT) {
  int n = blockIdx.x * 4 + (threadIdx.x >> 6);
  int lane = threadIdx.x & 63;
  if (n >= NN) return;
  float dn = dis[n];
  ushort4 v = ((const ushort4*)(H + (size_t)n * D1))[lane];
  float wsf = dn * dn;
  float a0 = wsf * bf2f(v.x), a1 = wsf * bf2f(v.y);
  float a2 = wsf * bf2f(v.z), a3 = wsf * bf2f(v.w);
  int e = row_ptr[n], e1 = row_ptr[n + 1];
  for (; e + 1 < e1; e += 2) {
    int sa = col[e], sb = col[e + 1];
    float wa = dis[sa] * dn, wb = dis[sb] * dn;
    ushort4 ua = ((const ushort4*)(H + (size_t)sa * D1))[lane];
    ushort4 ub = ((const ushort4*)(H + (size_t)sb * D1))[lane];
    a0 += wa * bf2f(ua.x) + wb * bf2f(ub.x);
    a1 += wa * bf2f(ua.y) + wb * bf2f(ub.y);
    a2 += wa * bf2f(ua.z) + wb * bf2f(ub.z);
    a3 += wa * bf2f(ua.w) + wb * bf2f(ub.w);
  }
  if (e < e1) {
    int sa = col[e];
    float wa = dis[sa] * dn;
    ushort4 ua = ((const ushort4*)(H + (size_t)sa * D1))[lane];
    a0 += wa * bf2f(ua.x);
    a1 += wa * bf2f(ua.y);
    a2 += wa * bf2f(ua.z);
    a3 += wa * bf2f(ua.w);
  }
  int c = lane * 4;
  a0 += bias[c]; a1 += bias[c + 1]; a2 += bias[c + 2]; a3 += bias[c + 3];
  ushort4 o;
  o.x = f2bf(a0); o.y = f2bf(a1); o.z = f2bf(a2); o.w = f2bf(a3);
  ((ushort4*)(OUT + (size_t)n * D1))[lane] = o;
}

__global__ __launch_bounds__(256) void k_agg2(const unsigned short* __restrict__ H,
                                              const int* __restrict__ row_ptr,
                                              const int* __restrict__ col,
                                              const float* __restrict__ dis,
                                              const float* __restrict__ bias,
                                              float* __restrict__ OUT) {
  int n = blockIdx.x * 4 + (threadIdx.x >> 6);
  int lane = threadIdx.x & 63;
  if (n >= NN) return;
  float dn = dis[n];
  ushort2 v = ((const ushort2*)(H + (size_t)n * D2))[lane];
  float wsf = dn * dn;
  float a0 = wsf * bf2f(v.x), a1 = wsf * bf2f(v.y);
  int e = row_ptr[n], e1 = row_ptr[n + 1];
  for (; e + 1 < e1; e += 2) {
    int sa = col[e], sb = col[e + 1];
    float wa = dis[sa] * dn, wb = dis[sb] * dn;
    ushort2 ua = ((const ushort2*)(H + (size_t)sa * D2))[lane];
    ushort2 ub = ((const ushort2*)(H + (size_t)sb * D2))[lane];
    a0 += wa * bf2f(ua.x) + wb * bf2f(ub.x);
    a1 += wa * bf2f(ua.y) + wb * bf2f(ub.y);
  }
  if (e < e1) {
    int sa = col[e];
    float wa = dis[sa] * dn;
    ushort2 ua = ((const ushort2*)(H + (size_t)sa * D2))[lane];
    a0 += wa * bf2f(ua.x);
    a1 += wa * bf2f(ua.y);
  }
  int c = lane * 2;
  a0 += bias[c]; a1 += bias[c + 1];
  ((float2*)(OUT + (size_t)n * D2))[lane] = make_float2(a0, a1);
}

// ---------- BatchNorm ----------
__global__ void k_stats1(const unsigned short* __restrict__ X, float* __restrict__ stats) {
  int t = threadIdx.x;  // column 0..255
  int r0 = blockIdx.x * 64;
  int r1 = (r0 + 64 < NN) ? r0 + 64 : NN;
  float s = 0.f, q = 0.f;
  for (int r = r0; r < r1; r++) {
    float v = bf2f(X[(size_t)r * D1 + t]);
    s += v;
    q += v * v;
  }
  atomicAdd(&stats[t], s);
  atomicAdd(&stats[D1 + t], q);
}

__global__ void k_apply1(unsigned short* __restrict__ X, const float* __restrict__ stats,
                         const float* __restrict__ gamma, const float* __restrict__ beta) {
  int i = blockIdx.x * blockDim.x + threadIdx.x;
  int c = i & (D1 - 1);
  float mean = stats[c] * (1.0f / NN);
  float var = stats[D1 + c] * (1.0f / NN) - mean * mean;
  float sc = gamma[c] * rsqrtf(var + EPSV);
  float v = (bf2f(X[i]) - mean) * sc + beta[c];
  X[i] = f2bf(fmaxf(v, 0.0f));  // fused ReLU
}

__global__ void k_stats2(const float* __restrict__ X, float* __restrict__ stats) {
  int t = threadIdx.x;  // column 0..127
  int r0 = blockIdx.x * 128;
  int r1 = (r0 + 128 < NN) ? r0 + 128 : NN;
  float s = 0.f, q = 0.f;
  for (int r = r0; r < r1; r++) {
    float v = X[(size_t)r * D2 + t];
    s += v;
    q += v * v;
  }
  atomicAdd(&stats[t], s);
  atomicAdd(&stats[D2 + t], q);
}

__global__ void k_apply2(float* __restrict__ X, const float* __restrict__ stats,
                         const float* __restrict__ gamma, const float* __restrict__ beta) {
  int i = blockIdx.x * blockDim.x + threadIdx.x;
  int c = i & (D2 - 1);
  float mean = stats[c] * (1.0f / NN);
  float var = stats[D2 + c] * (1.0f / NN) - mean * mean;
  float sc = gamma[c] * rsqrtf(var + EPSV);
  X[i] = (X[i] - mean) * sc + beta[c];
}

extern "C" void kernel_launch(void* const* d_in, const int* in_sizes, int n_in,
                              void* d_out, int out_size, void* d_ws, size_t ws_size,
                              hipStream_t stream) {
  const float* x  = (const float*)d_in[0];
  const int* ei   = (const int*)d_in[1];  // [2, NE], int32
  const int* srcv = ei;
  const int* dstv = ei + NE;
  const float* W1  = (const float*)d_in[2];
  const float* b1  = (const float*)d_in[3];
  const float* g1  = (const float*)d_in[4];
  const float* be1 = (const float*)d_in[5];
  const float* W2  = (const float*)d_in[6];
  const float* b2  = (const float*)d_in[7];
  const float* g2  = (const float*)d_in[8];
  const float* be2 = (const float*)d_in[9];
  float* out = (float*)d_out;

  char* ws = (char*)d_ws;
  size_t off = 0;
  auto alloc = [&](size_t bytes) {
    size_t cur = off;
    off = (off + bytes + 255) & ~(size_t)255;
    return cur;
  };
  int* cnt       = (int*)(ws + alloc(NN * 4));
  int* row_ptr   = (int*)(ws + alloc((NN + 1) * 4));
  int* cursor    = (int*)(ws + alloc(NN * 4));
  float* dis     = (float*)(ws + alloc(NN * 4));
  int* part      = (int*)(ws + alloc(256 * 4));
  float* stats   = (float*)(ws + alloc((D1 * 2 + D2 * 2) * 4));
  int* col       = (int*)(ws + alloc((size_t)NE * 4));
  unsigned short* H1  = (unsigned short*)(ws + alloc((size_t)NN * D1 * 2));
  unsigned short* A1  = (unsigned short*)(ws + alloc((size_t)NN * D1 * 2));
  unsigned short* H2  = (unsigned short*)(ws + alloc((size_t)NN * D2 * 2));
  unsigned short* W1t = (unsigned short*)(ws + alloc((size_t)DIN * D1 * 2));
  unsigned short* W2t = (unsigned short*)(ws + alloc((size_t)D1 * D2 * 2));
  float* stats2 = stats + D1 * 2;

  const int nb = (NN + 255) / 256;  // 196

  // CSR build
  k_zero<<<nb, 256, 0, stream>>>(cnt, stats);
  k_hist<<<NE / 256, 256, 0, stream>>>(dstv, cnt);
  k_scan_partial<<<nb, 256, 0, stream>>>(cnt, part);
  k_scan_block<<<1, 256, 0, stream>>>(part, nb);
  k_scan_final<<<nb, 256, 0, stream>>>(cnt, part, row_ptr, cursor, dis);
  k_fill<<<NE / 256, 256, 0, stream>>>(srcv, dstv, cursor, col);

  // weight transpose + bf16 convert
  k_prep_w<<<(DIN * D1 + D1 * D2) / 256, 256, 0, stream>>>(W1, W2, W1t, W2t);

  const int mb = (NN + 127) / 128;  // 391

  // conv1: H1 = x@W1 (MFMA) ; A1 = agg(H1)+b1 ; BN1+ReLU in place
  k_gemm_mfma<DIN, true><<<dim3(mb, D1 / 128), 256, 0, stream>>>(x, W1t, H1, NN, D1);
  k_agg1<<<(NN + 3) / 4, 256, 0, stream>>>(H1, row_ptr, col, dis, b1, A1);
  k_stats1<<<(NN + 63) / 64, 256, 0, stream>>>(A1, stats);
  k_apply1<<<NN * D1 / 256, 256, 0, stream>>>(A1, stats, g1, be1);

  // conv2: H2 = A1@W2 (MFMA) ; out = agg(H2)+b2 ; BN2 in place
  k_gemm_mfma<D1, false><<<dim3(mb, D2 / 128), 256, 0, stream>>>(A1, W2t, H2, NN, D2);
  k_agg2<<<(NN + 3) / 4, 256, 0, stream>>>(H2, row_ptr, col, dis, b2, out);
  k_stats2<<<(NN + 127) / 128, 128, 0, stream>>>(out, stats2);
  k_apply2<<<NN * D2 / 256, 256, 0, stream>>>(out, stats2, g2, be2);
}